// Round 1
// 1078.648 us; speedup vs baseline: 1.1471x; 1.1471x over previous
//
#include <hip/hip_runtime.h>

#define N_NODES 50000
#define N_EDGES 800000

typedef __attribute__((ext_vector_type(8))) short short8;
typedef __attribute__((ext_vector_type(4))) float floatx4;
typedef __attribute__((ext_vector_type(4))) unsigned int u32x4;
typedef __attribute__((ext_vector_type(2))) __bf16 bf16x2;
typedef unsigned short ushort_t;
typedef unsigned int uint_t;

// compiler-native bf16 converts: emits v_cvt_pk_bf16_f32 (RNE), 1 inst
__device__ __forceinline__ uint_t pkbf(float lo, float hi){
  bf16x2 v = { (__bf16)lo, (__bf16)hi };
  return __builtin_bit_cast(uint_t, v);
}
__device__ __forceinline__ ushort_t f2bf(float f){
  return __builtin_bit_cast(ushort_t, (__bf16)f);
}
__device__ __forceinline__ float bf2f(ushort_t h){
  unsigned u = ((unsigned)h) << 16;
  return __builtin_bit_cast(float, u);
}
// sigmoid via v_rcp_f32 (avoid IEEE div sequence)
__device__ __forceinline__ float sigm(float x){
  return __builtin_amdgcn_rcpf(1.f + __expf(-x));
}
// tanh via exp+rcp: tanh(|x|) = 1 - 2/(e^{2|x|}+1); |x|->inf handled (rcp(inf)=0)
__device__ __forceinline__ float tanh_f(float x){
  float ax = fabsf(x);
  float t = 1.f - 2.f*__builtin_amdgcn_rcpf(__expf(2.f*ax) + 1.f);
  return copysignf(t, x);
}
__device__ __forceinline__ float waveRed(float v){
  #pragma unroll
  for (int o=32;o>0;o>>=1) v += __shfl_xor(v,o);
  return v;
}
__device__ __forceinline__ int ldIdx(const int* __restrict__ idx, long long pos, int mode){
  return mode ? idx[pos*2] : idx[pos];
}
__device__ __forceinline__ short8 as_s8(u32x4 v){ return __builtin_bit_cast(short8, v); }

// async global->LDS 16B: lds dest = wave-uniform base + lane*16
__device__ __forceinline__ void gl_lds16(const ushort_t* g, ushort_t* l){
  __builtin_amdgcn_global_load_lds(
    (const __attribute__((address_space(1))) unsigned int*)(unsigned long long)(uintptr_t)g,
    (__attribute__((address_space(3))) unsigned int*)(unsigned int)(uintptr_t)l,
    16, 0, 0);
}

__device__ __forceinline__ u32x4 bfadd8(u32x4 a, u32x4 b){
  u32x4 r;
  #pragma unroll
  for (int i=0;i<4;++i){
    float alo = __builtin_bit_cast(float, a[i]<<16);
    float ahi = __builtin_bit_cast(float, a[i]&0xffff0000u);
    float blo = __builtin_bit_cast(float, b[i]<<16);
    float bhi = __builtin_bit_cast(float, b[i]&0xffff0000u);
    r[i] = pkbf(alo+blo, ahi+bhi);
  }
  return r;
}
__device__ __forceinline__ short8 pack8(floatx4 x, floatx4 y){
  u32x4 u;
  u[0] = pkbf(x[0], x[1]); u[1] = pkbf(x[2], x[3]);
  u[2] = pkbf(y[0], y[1]); u[3] = pkbf(y[2], y[3]);
  return __builtin_bit_cast(short8, u);
}

// ---------------- prep kernels ----------------

__global__ void kDetect(const int* __restrict__ idx, int* __restrict__ flag){
  if (threadIdx.x==0 && blockIdx.x==0){
    int any = 0;
    for (int i=1;i<64;i+=2) any |= idx[i];   // all-zero odd dwords => int64
    *flag = (any==0) ? 1 : 0;
  }
}

__global__ void kLN(const float* __restrict__ s, const float* __restrict__ g,
                    const float* __restrict__ b, ushort_t* __restrict__ out, int N){
  int wid = threadIdx.x >> 6, lane = threadIdx.x & 63;
  int n = blockIdx.x*4 + wid;
  if (n >= N) return;
  float x0 = s[(size_t)n*128 + lane], x1 = s[(size_t)n*128 + 64 + lane];
  float sum = waveRed(x0 + x1);
  float sq  = waveRed(x0*x0 + x1*x1);
  float mean = sum * (1.f/128.f);
  float var  = sq * (1.f/128.f) - mean*mean;
  float rstd = rsqrtf(var + 1e-5f);
  out[(size_t)n*128 + lane]      = f2bf((x0-mean)*rstd*g[lane] + b[lane]);
  out[(size_t)n*128 + 64 + lane] = f2bf((x1-mean)*rstd*g[64+lane] + b[64+lane]);
}

// W[K][OUT] f32 -> bf16 Wp[kt][q][n][j] (k = kt*32+q*8+j): B-frag = contiguous 16B
__global__ void kReorder(const float* __restrict__ W, ushort_t* __restrict__ Wp,
                         int K, int OUT){
  int total = K*OUT;
  for (int o = blockIdx.x*blockDim.x + threadIdx.x; o < total; o += gridDim.x*blockDim.x){
    int j = o & 7; int rest = o >> 3;
    int nn = rest % OUT; int qk = rest / OUT;
    int q = qk & 3, kt = qk >> 2;
    int k = kt*32 + q*8 + j;
    Wp[o] = f2bf(W[(size_t)k*OUT + nn]);
  }
}

// Wab[k<128][n<640]: n<320 -> e_w1[k][n] (tgt), n>=320 -> e_w1[128+k][n-320] (src)
__global__ void kReorderAB(const float* __restrict__ W, ushort_t* __restrict__ Wp){
  int total = 128*640;
  for (int o = blockIdx.x*blockDim.x + threadIdx.x; o < total; o += gridDim.x*blockDim.x){
    int j = o & 7; int rest = o >> 3;
    int nn = rest % 640; int qk = rest / 640;
    int q = qk & 3, kt = qk >> 2;
    int k = kt*32 + q*8 + j;
    float v = (nn < 320) ? W[(size_t)k*320 + nn] : W[(size_t)(128+k)*320 + (nn-320)];
    Wp[o] = f2bf(v);
  }
}

// ---------------- counting sort of edges by tgt ----------------

__global__ void kHist(const int* __restrict__ idx, const int* __restrict__ flagp,
                      int* __restrict__ counts){
  int mode = *flagp;
  long long e = (long long)blockIdx.x*256 + threadIdx.x;
  if (e < N_EDGES) atomicAdd(&counts[ldIdx(idx, e, mode)], 1);
}

// 3-kernel scan: per-block shuffle scan, block-sums scan, add-back.
__global__ void kScanLocal(const int* __restrict__ counts, int* __restrict__ offsets,
                           int* __restrict__ bsum, int n){
  int tid = threadIdx.x, lane = tid & 63, wid = tid >> 6;
  int i = blockIdx.x*1024 + tid;
  int x = (i<n) ? counts[i] : 0;
  int v = x;
  #pragma unroll
  for (int o=1;o<64;o<<=1){ int t = __shfl_up(v,o); if (lane>=o) v += t; }
  __shared__ int ws[16];
  if (lane==63) ws[wid] = v;
  __syncthreads();
  if (wid==0){
    int s = (lane<16) ? ws[lane] : 0;
    #pragma unroll
    for (int o=1;o<16;o<<=1){ int t = __shfl_up(s,o); if (lane>=o) s += t; }
    if (lane<16) ws[lane] = s;
  }
  __syncthreads();
  int base = wid ? ws[wid-1] : 0;
  if (i<n) offsets[i] = base + v - x;           // block-local exclusive
  if (tid==1023) bsum[blockIdx.x] = ws[15];
}
__global__ void kScanSums(const int* __restrict__ bsum, int* __restrict__ bbase, int nb){
  int lane = threadIdx.x;
  int x = (lane<nb) ? bsum[lane] : 0;
  int v = x;
  #pragma unroll
  for (int o=1;o<64;o<<=1){ int t = __shfl_up(v,o); if (lane>=o) v += t; }
  if (lane<nb) bbase[lane] = v - x;
}
__global__ void kScanAdd(int* __restrict__ offsets, int* __restrict__ cursor,
                         const int* __restrict__ bbase, int n){
  int i = blockIdx.x*1024 + threadIdx.x;
  if (i<n){ int v = offsets[i] + bbase[blockIdx.x]; offsets[i]=v; cursor[i]=v; }
}

// scatter: sorted pos -> edge id, tgt (u16), aux {src, unit xyz} (16B)
__global__ void kScatter(const int* __restrict__ idx, const int* __restrict__ flagp,
                         int* __restrict__ cursor, const float* __restrict__ edge_vector,
                         int* __restrict__ sortedE, ushort_t* __restrict__ sortedT,
                         floatx4* __restrict__ aux){
  int mode = *flagp;
  long long e = (long long)blockIdx.x*256 + threadIdx.x;
  if (e < N_EDGES){
    int t = ldIdx(idx, e, mode);
    int s = ldIdx(idx, (long long)N_EDGES + e, mode);
    float ex = edge_vector[e*3], ey = edge_vector[e*3+1], ez = edge_vector[e*3+2];
    float inr = 1.f / fmaxf(sqrtf(ex*ex+ey*ey+ez*ez), 1e-8f);
    int pos = atomicAdd(&cursor[t], 1);
    sortedE[pos] = (int)e;
    sortedT[pos] = (ushort_t)t;
    floatx4 a; a[0] = __int_as_float(s); a[1] = ex*inr; a[2] = ey*inr; a[3] = ez*inr;
    aux[pos] = a;
  }
}

// ---------------- node-level P: P[n][0:320]=s_norm@W1a+b1, [320:640]=s_norm@W1b ----
__global__ __launch_bounds__(256,2) void kNodeP(
  const ushort_t* __restrict__ s_norm, const ushort_t* __restrict__ Wabp,
  const float* __restrict__ b1, ushort_t* __restrict__ P)
{
  __shared__ u32x4 sA[1024];   // 16KB
  __shared__ u32x4 sB[2560];   // 40KB
  const int tid = threadIdx.x;
  const int lane = tid & 63, wid = tid >> 6;
  const int col = lane & 15, quad = lane >> 4;
  const int nb0 = blockIdx.x * 64;

  for (int i=0;i<4;++i){
    int d = i*256 + tid;
    int m=d&15, q=(d>>4)&3, mt=(d>>6)&3, kt=d>>8;
    int node = nb0 + mt*16 + m;
    u32x4 v = {0,0,0,0};
    if (node < N_NODES) v = *(const u32x4*)(s_norm + (size_t)node*128 + (kt*4+q)*8);
    sA[d] = v;
  }

  const floatx4 zz = {0.f,0.f,0.f,0.f};
  floatx4 acc[10][4];
  #pragma unroll
  for (int i=0;i<10;++i)
    #pragma unroll
    for (int j=0;j<4;++j) acc[i][j] = zz;

  for (int kt=0; kt<4; ++kt){
    for (int i=0;i<10;++i){
      int cb = i*256 + wid*64;
      gl_lds16(Wabp + ((size_t)kt*2560 + cb + lane)*8, (ushort_t*)&sB[cb]);
    }
    __syncthreads();
    short8 a[4];
    #pragma unroll
    for (int mt=0; mt<4; ++mt)
      a[mt] = as_s8(sA[((kt*4+mt)*4+quad)*16 + col]);
    #pragma unroll
    for (int nt=0; nt<10; ++nt){
      int n = wid*160 + nt*16 + col;
      short8 b = as_s8(sB[quad*640 + n]);
      #pragma unroll
      for (int mt=0; mt<4; ++mt)
        acc[nt][mt] = __builtin_amdgcn_mfma_f32_16x16x32_bf16(a[mt], b, acc[nt][mt], 0,0,0);
    }
    __syncthreads();
  }

  #pragma unroll
  for (int nt=0; nt<10; ++nt){
    int n = wid*160 + nt*16 + col;
    float bias = (n < 320) ? b1[n] : 0.f;
    #pragma unroll
    for (int mt=0; mt<4; ++mt)
      #pragma unroll
      for (int reg=0; reg<4; ++reg){
        int node = nb0 + mt*16 + quad*4 + reg;
        if (node < N_NODES)
          P[(size_t)node*640 + n] = f2bf(acc[nt][mt][reg] + bias);
      }
  }
}

// ---------------- fused edge MLP v4 ----------------
// Changes vs v3:
//  * wave->column map: wave w owns n in {32w..32w+31} u {128+32w..128+32w+31}
//    u {256+16w..256+16w+15}, so upd[n] and upd[n+128] live in the SAME thread
//    (nt pairs 0<->2, 1<->3) -> gating fully in registers, epi2 + gating loop
//    + 2 barriers + ~40k scalar LDS ops per block eliminated.
//  * staging: r/quad constant per thread, kt == i -> tgt/src + row pointers
//    hoisted; sTgt/sSrc/sE LDS arrays and first barrier removed (LDS = 40KB).
//  * sigm via v_rcp, f2bf/pkbf via native __bf16 casts (1 inst).
__global__ __launch_bounds__(256,3) void kEdgeMLP(
    const ushort_t* __restrict__ P, const float* __restrict__ edge_attr,
    const ushort_t* __restrict__ W1cp, const ushort_t* __restrict__ W2p,
    const float* __restrict__ b2, const int* __restrict__ sortedE,
    const ushort_t* __restrict__ sortedT, const floatx4* __restrict__ aux,
    ushort_t* __restrict__ msg)
{
  __shared__ u32x4 sA[2560];          // 40KB exactly: P-sum -> h (frag order)
  const int tid = threadIdx.x;
  const int lane = tid & 63, wid = tid >> 6;
  const int col = lane & 15, quad = lane >> 4;
  const long long p0 = (long long)blockIdx.x * 64;

  // column map (bijective over [0,320))
  int ncol[5];
  ncol[0] = wid*32 + col;
  ncol[1] = ncol[0] + 16;
  ncol[2] = ncol[0] + 128;
  ncol[3] = ncol[0] + 144;
  ncol[4] = 256 + wid*16 + col;

  // edge ids for A-fragment gather (direct from global, L1-cached)
  int eId[4];
  #pragma unroll
  for (int mt=0;mt<4;++mt) eId[mt] = sortedE[p0 + mt*16 + col];

  // edge_attr A-fragments (gathered rows, 256B-aligned) -> registers
  short8 aQ[2][4];
  #pragma unroll
  for (int kq=0; kq<2; ++kq)
    #pragma unroll
    for (int mt=0; mt<4; ++mt){
      const float* fp = edge_attr + (size_t)eId[mt]*64 + kq*32 + quad*8;
      aQ[kq][mt] = pack8(*(const floatx4*)fp, *(const floatx4*)(fp+4));
    }

  // stage sP = P[tgt][n] + P[src][320+n] into sA (A-frag order over k=n).
  // For d = i*256+tid: m=tid&15, q=quad, mt=wid, kt=i -> all loop-invariant
  // except kt. One tgt/src fetch + two row pointers per thread.
  {
    const int r = wid*16 + col;
    int tgt = (int)sortedT[p0 + r];
    int src = __float_as_int(((const float*)aux)[(size_t)(p0 + r)*4]);
    const u32x4* pT = (const u32x4*)(P + (size_t)tgt*640) + quad;
    const u32x4* pS = (const u32x4*)(P + (size_t)src*640 + 320) + quad;
    #pragma unroll
    for (int i=0;i<10;++i)
      sA[i*256 + tid] = bfadd8(pT[i*4], pS[i*4]);
  }
  __syncthreads();

  const floatx4 zz = {0.f,0.f,0.f,0.f};
  floatx4 acc[5][4];
  #pragma unroll
  for (int i=0;i<5;++i)
    #pragma unroll
    for (int j=0;j<4;++j) acc[i][j] = zz;

  // GEMM1: edge_attr @ W1c (K=64), B direct from global (L2-resident)
  #pragma unroll
  for (int kq=0; kq<2; ++kq)
    #pragma unroll
    for (int nt=0; nt<5; ++nt){
      short8 b = as_s8(*(const u32x4*)(W1cp + ((size_t)(kq*4+quad)*320 + ncol[nt])*8));
      #pragma unroll
      for (int mt=0; mt<4; ++mt)
        acc[nt][mt] = __builtin_amdgcn_mfma_f32_16x16x32_bf16(aQ[kq][mt], b, acc[nt][mt], 0,0,0);
    }

  // epi1: h = silu(acc + sP) in place (per-element owner bijection holds for
  // any bijective column map). DS offsets fold into immediates.
  ushort_t* sH16 = (ushort_t*)sA;
  #pragma unroll
  for (int nt=0; nt<5; ++nt){
    int n = ncol[nt];
    ushort_t* hp = sH16 + (((n>>5)*256 + ((n>>3)&3)*16 + quad*4)*8 + (n&7));
    #pragma unroll
    for (int mt=0; mt<4; ++mt)
      #pragma unroll
      for (int reg=0; reg<4; ++reg){
        int a2 = mt*512 + reg*8;
        float x = acc[nt][mt][reg] + bf2f(hp[a2]);
        hp[a2] = f2bf(x * sigm(x));
      }
  }
  #pragma unroll
  for (int i=0;i<5;++i)
    #pragma unroll
    for (int j=0;j<4;++j) acc[i][j] = zz;
  __syncthreads();

  // bias preload for fused epilogue
  float b2c[5];
  #pragma unroll
  for (int nt=0;nt<5;++nt) b2c[nt] = b2[ncol[nt]];

  // GEMM2: K=320 in 10 K=32 rounds, B direct from global, NO barriers
  const ushort_t* w2q = W2p + (size_t)quad*320*8;
  for (int kt=0; kt<10; ++kt){
    short8 bfr[5];
    #pragma unroll
    for (int nt=0; nt<5; ++nt)
      bfr[nt] = as_s8(*(const u32x4*)(w2q + (size_t)kt*10240 + (size_t)ncol[nt]*8));
    short8 a[4];
    #pragma unroll
    for (int mt=0; mt<4; ++mt)
      a[mt] = as_s8(sA[((kt*4+mt)*4+quad)*16 + col]);
    #pragma unroll
    for (int nt=0; nt<5; ++nt)
      #pragma unroll
      for (int mt=0; mt<4; ++mt)
        acc[nt][mt] = __builtin_amdgcn_mfma_f32_16x16x32_bf16(a[mt], bfr[nt], acc[nt][mt], 0,0,0);
  }

  // fused epilogue: bias + gating entirely in registers -> msg.
  //   sm[n]      = upd[n] * sigm(upd[n+128])   (nt pairs 0/2 and 1/3)
  //   msg[128+v] = sigm(upd[256+v])  (wid 0,1) ; msg[160+v] = upd[288+v] (wid 2,3)
  //   dest for nt4 collapses to 128 + wid*16 + col for ALL wids.
  #pragma unroll
  for (int mt=0; mt<4; ++mt)
    #pragma unroll
    for (int reg=0; reg<4; ++reg){
      int row = mt*16 + quad*4 + reg;
      ushort_t* mrow = msg + (size_t)(p0 + row)*192;
      float a0 = acc[0][mt][reg] + b2c[0];
      float g0 = acc[2][mt][reg] + b2c[2];
      mrow[ncol[0]] = f2bf(a0 * sigm(g0));
      float a1 = acc[1][mt][reg] + b2c[1];
      float g1 = acc[3][mt][reg] + b2c[3];
      mrow[ncol[1]] = f2bf(a1 * sigm(g1));
      float v4 = acc[4][mt][reg] + b2c[4];
      float ov = (wid < 2) ? sigm(v4) : v4;     // wave-uniform branch
      mrow[ncol[4] - 128] = f2bf(ov);
    }
}

// ---------------- per-node aggregation (contiguous msg rows) ----------------
__global__ __launch_bounds__(128) void kAgg(
  const ushort_t* __restrict__ msg, const floatx4* __restrict__ aux,
  const int* __restrict__ counts, const int* __restrict__ offsets,
  const float* __restrict__ scalar_state, const float* __restrict__ vector_state,
  const float* __restrict__ pn_g, const float* __restrict__ pn_b,
  float* __restrict__ outS, float* __restrict__ outV, ushort_t* __restrict__ node_in)
{
  int n = blockIdx.x, t = threadIdx.x;
  int cnt = counts[n], start = offsets[n];
  int c = t >> 5, vv = t & 31;
  float accS = 0.f, accV = 0.f;
  for (int i=0; i<cnt; ++i){
    const ushort_t* row = msg + (size_t)(start+i)*192;
    accS += bf2f(row[t]);
    if (t < 96){
      floatx4 a = aux[start+i];
      int src = __float_as_int(a[0]);
      float sg  = bf2f(row[128+vv]);
      float dsv = bf2f(row[160+vv]);
      float sv = vector_state[(size_t)src*96 + t];
      float uc = (c==0) ? a[1] : (c==1) ? a[2] : a[3];
      accV += sv*sg + uc*dsv;
    }
  }
  float inv = 1.f / fmaxf((float)cnt, 1.f);
  __shared__ float lv[96];
  __shared__ float pS[2], pQ[2];
  float s1 = scalar_state[(size_t)n*128 + t] + accS*inv;
  outS[(size_t)n*128 + t] = s1;
  if (t < 96){
    float v1 = vector_state[(size_t)n*96 + t] + accV*inv;
    outV[(size_t)n*96 + t] = v1;
    lv[t] = v1;
  }
  float wsum = waveRed(s1), wsq = waveRed(s1*s1);
  if ((t&63)==0){ pS[t>>6]=wsum; pQ[t>>6]=wsq; }
  __syncthreads();
  float mean = (pS[0]+pS[1]) * (1.f/128.f);
  float var  = (pQ[0]+pQ[1]) * (1.f/128.f) - mean*mean;
  float rstd = rsqrtf(var + 1e-5f);
  node_in[(size_t)n*160 + t] = f2bf((s1-mean)*rstd*pn_g[t] + pn_b[t]);
  if (t < 32){
    float a = lv[t], b = lv[32+t], d = lv[64+t];
    float vn = sqrtf(fmaxf(a*a+b*b+d*d, 1e-8f));
    node_in[(size_t)n*160 + 128 + t] = f2bf(vn);
  }
}

// ---------------- fused node MLP (direct-global B, 2 barriers) ----------------
__global__ __launch_bounds__(256,2) void kNodeMLP(
  const ushort_t* __restrict__ node_in, const ushort_t* __restrict__ W1np,
  const ushort_t* __restrict__ W2np, const float* __restrict__ b1,
  const float* __restrict__ b2, float* __restrict__ outS, float* __restrict__ outV)
{
  __shared__ u32x4 sA[640];    // 10KB
  __shared__ u32x4 sH[1152];   // 18KB
  const int tid = threadIdx.x;
  const int lane = tid & 63, wid = tid >> 6;
  const int col = lane & 15, quad = lane >> 4;
  const int wm = wid & 1, wn = wid >> 1;
  const int rbase = blockIdx.x * 32;

  for (int d = tid; d < 640; d += 256){
    int m = d & 15, q = (d>>4)&3, mtile = (d>>6)&1, kt = d>>7;
    int r = rbase + mtile*16 + m, cc = kt*4 + q;
    u32x4 v = {0,0,0,0};
    if (r < N_NODES) v = *(const u32x4*)(node_in + (size_t)r*160 + cc*8);
    sA[d] = v;
  }
  __syncthreads();

  const floatx4 zz = {0.f,0.f,0.f,0.f};
  floatx4 acc[9];
  #pragma unroll
  for (int i=0;i<9;++i) acc[i] = zz;

  for (int kt=0; kt<5; ++kt){
    short8 a = as_s8(sA[((kt*2+wm)*4+quad)*16 + col]);
    #pragma unroll
    for (int jt=0; jt<9; ++jt){
      int n = wn*144 + jt*16 + col;
      short8 b = as_s8(*(const u32x4*)(W1np + (size_t)kt*9216 + ((size_t)quad*288 + n)*8));
      acc[jt] = __builtin_amdgcn_mfma_f32_16x16x32_bf16(a, b, acc[jt], 0,0,0);
    }
  }
  ushort_t* sH16 = (ushort_t*)sH;
  #pragma unroll
  for (int jt=0; jt<9; ++jt){
    int n = wn*144 + jt*16 + col;
    float bias = b1[n];
    int kt_h = n>>5, q_h = (n>>3)&3, j_h = n&7;
    #pragma unroll
    for (int reg=0; reg<4; ++reg){
      int ml = quad*4 + reg;
      float x = acc[jt][reg] + bias;
      float s = x * sigm(x);
      int chunk = ((kt_h*2 + wm)*4 + q_h)*16 + ml;
      sH16[chunk*8 + j_h] = f2bf(s);
    }
  }
  __syncthreads();

  floatx4 acc2[5];
  #pragma unroll
  for (int i=0;i<5;++i) acc2[i] = zz;

  for (int kt=0; kt<9; ++kt){
    short8 a = as_s8(sH[((kt*2+wm)*4+quad)*16 + col]);
    #pragma unroll
    for (int jt=0; jt<5; ++jt){
      int n = wn*80 + jt*16 + col;
      short8 b = as_s8(*(const u32x4*)(W2np + (size_t)kt*5120 + ((size_t)quad*160 + n)*8));
      acc2[jt] = __builtin_amdgcn_mfma_f32_16x16x32_bf16(a, b, acc2[jt], 0,0,0);
    }
  }

  #pragma unroll
  for (int jt=0; jt<5; ++jt){
    int n = wn*80 + jt*16 + col;
    float bias = b2[n];
    #pragma unroll
    for (int reg=0; reg<4; ++reg){
      int ml = quad*4 + reg;
      int r = rbase + wm*16 + ml;
      if (r < N_NODES){
        float val = acc2[jt][reg] + bias;
        if (n < 128){
          float* o = outS + (size_t)r*128 + n;
          *o = *o + val;
        } else {
          int vv = n - 128;
          float f = 1.f + 0.1f * tanh_f(val);
          float* o = outV + (size_t)r*96 + vv;
          o[0] *= f; o[32] *= f; o[64] *= f;
        }
      }
    }
  }
}

// ---------------- launch ----------------

extern "C" void kernel_launch(void* const* d_in, const int* in_sizes, int n_in,
                              void* d_out, int out_size, void* d_ws, size_t ws_size,
                              hipStream_t stream)
{
  const float* scalar_state = (const float*)d_in[0];
  const float* vector_state = (const float*)d_in[1];
  const float* edge_attr    = (const float*)d_in[2];
  const float* edge_vector  = (const float*)d_in[3];
  const float* sn_g = (const float*)d_in[4];
  const float* sn_b = (const float*)d_in[5];
  const float* pn_g = (const float*)d_in[6];
  const float* pn_b = (const float*)d_in[7];
  const float* e_w1 = (const float*)d_in[8];
  const float* e_b1 = (const float*)d_in[9];
  const float* e_w2 = (const float*)d_in[10];
  const float* e_b2 = (const float*)d_in[11];
  const float* n_w1 = (const float*)d_in[12];
  const float* n_b1 = (const float*)d_in[13];
  const float* n_w2 = (const float*)d_in[14];
  const float* n_b2 = (const float*)d_in[15];
  const int*   eidx = (const int*)d_in[16];

  char* p = (char*)d_ws;
  auto take = [&](size_t bytes)->char*{
    char* r = p; p += (bytes + 255) & ~(size_t)255; return r;
  };
  int*      flag    = (int*)take(4);
  ushort_t* s_norm  = (ushort_t*)take((size_t)N_NODES*128*2);
  ushort_t* Wabp    = (ushort_t*)take((size_t)128*640*2);
  ushort_t* W1cp    = (ushort_t*)take((size_t)64*320*2);
  ushort_t* W2p     = (ushort_t*)take((size_t)320*320*2);
  ushort_t* W1np    = (ushort_t*)take((size_t)160*288*2);
  ushort_t* W2np    = (ushort_t*)take((size_t)288*160*2);
  int*      counts  = (int*)take((size_t)N_NODES*4);
  int*      offsets = (int*)take((size_t)N_NODES*4);
  int*      cursor  = (int*)take((size_t)N_NODES*4);
  int*      bsum    = (int*)take(64*4);
  int*      bbase   = (int*)take(64*4);
  int*      sortedE = (int*)take((size_t)N_EDGES*4);
  ushort_t* sortedT = (ushort_t*)take((size_t)N_EDGES*2);
  floatx4*  aux     = (floatx4*)take((size_t)N_EDGES*16);
  ushort_t* Pbuf    = (ushort_t*)take((size_t)N_NODES*640*2);
  ushort_t* msg     = (ushort_t*)take((size_t)N_EDGES*192*2);
  ushort_t* node_in = Pbuf;   // alias: Pbuf dead after kEdgeMLP, node_in born in kAgg
  (void)ws_size; (void)in_sizes; (void)n_in; (void)out_size;

  float* outS = (float*)d_out;
  float* outV = outS + (size_t)N_NODES*128;

  kDetect<<<1, 64, 0, stream>>>(eidx, flag);
  kLN<<<(N_NODES+3)/4, 256, 0, stream>>>(scalar_state, sn_g, sn_b, s_norm, N_NODES);
  kReorderAB<<<160, 256, 0, stream>>>(e_w1, Wabp);
  kReorder<<<160, 256, 0, stream>>>(e_w1 + (size_t)256*320, W1cp, 64, 320);
  kReorder<<<160, 256, 0, stream>>>(e_w2, W2p, 320, 320);
  kReorder<<<160, 256, 0, stream>>>(n_w1, W1np, 160, 288);
  kReorder<<<160, 256, 0, stream>>>(n_w2, W2np, 288, 160);
  hipMemsetAsync(counts, 0, (size_t)N_NODES*4, stream);
  kHist<<<N_EDGES/256, 256, 0, stream>>>(eidx, flag, counts);
  int nsb = (N_NODES + 1023)/1024;   // 49
  kScanLocal<<<nsb, 1024, 0, stream>>>(counts, offsets, bsum, N_NODES);
  kScanSums<<<1, 64, 0, stream>>>(bsum, bbase, nsb);
  kScanAdd<<<nsb, 1024, 0, stream>>>(offsets, cursor, bbase, N_NODES);
  kScatter<<<N_EDGES/256, 256, 0, stream>>>(eidx, flag, cursor, edge_vector,
                                            sortedE, sortedT, aux);
  kNodeP<<<(N_NODES+63)/64, 256, 0, stream>>>(s_norm, Wabp, e_b1, Pbuf);
  kEdgeMLP<<<N_EDGES/64, 256, 0, stream>>>(Pbuf, edge_attr, W1cp, W2p,
                                           e_b2, sortedE, sortedT, aux, msg);
  kAgg<<<N_NODES, 128, 0, stream>>>(msg, aux, counts, offsets,
                                    scalar_state, vector_state,
                                    pn_g, pn_b, outS, outV, node_in);
  kNodeMLP<<<(N_NODES+31)/32, 256, 0, stream>>>(node_in, W1np, W2np, n_b1, n_b2, outS, outV);
}